// Round 3
// baseline (397.323 us; speedup 1.0000x reference)
//
#include <hip/hip_runtime.h>
#include <stdint.h>

// Fused multi-scale ROIAlign (torchvision, aligned=false, sampling_ratio=2).
// R3: (a) x-adjacent bilinear taps merged into 8B paired loads (16 -> 8 loads
// per channel-iter); (b) level made block-uniform (levels padded to 256-thread
// multiples) so feature/output bases are SGPR-resident and per-lane offsets are
// 32-bit; (c) right-edge clamp folded into weights (lx==0 exactly when clamped).

#define C_CH 256
#define CC 32                 // channels per thread
#define NCHUNK (C_CH / CC)

struct F2 { float x, y; };    // alignment 4: compiler may merge to dwordx2 (HW
                              // unaligned-tolerant) or emit 2 offset-folded dwords.

struct Params {
    const float* feat[4];
    const float* boxes;
    long long outBase[4];     // element offset into out
    float scale[4];
    int hwShift[4];           // log2(HW)
    int pShift[4];            // log2(P)
    int workBase[5];          // cumulative PADDED work items per level
    int M;
};

__global__ __launch_bounds__(256, 4) void msroi_kernel(Params p, float* __restrict__ out)
{
    const int blockStart = blockIdx.x * 256;          // scalar
    const int lvl = (blockStart >= p.workBase[1])
                  + (blockStart >= p.workBase[2])
                  + (blockStart >= p.workBase[3]);    // scalar: blocks never straddle levels

    const int pSh  = p.pShift[lvl];
    const int hwSh = p.hwShift[lvl];
    const int HW   = 1 << hwSh;
    const int K    = 1 << (2 * pSh);
    const float sc = p.scale[lvl];
    const char* __restrict__ fB = (const char*)p.feat[lvl];          // SGPR base
    char* __restrict__ oB = (char*)(out + p.outBase[lvl]);           // SGPR base
    const int levelN = p.M << (2 * pSh + 3);          // M*K*NCHUNK (NCHUNK=8)

    int r = blockStart + threadIdx.x - p.workBase[lvl];
    if (r >= levelN) return;

    const int pixN  = p.M << (2 * pSh);
    const int chunk = r / pixN;                       // once per 32 channel-iters
    const int pix   = r - chunk * pixN;
    const int m     = pix >> (2 * pSh);
    const int pib   = pix & (K - 1);
    const int py    = pib >> pSh;
    const int px    = pib & ((1 << pSh) - 1);

    const float* bxp = p.boxes + m * 5;
    const int   b   = (int)bxp[0];
    const float rx1 = bxp[1] * sc;
    const float ry1 = bxp[2] * sc;
    const float rx2 = bxp[3] * sc;
    const float ry2 = bxp[4] * sc;
    const float invP  = 1.0f / (float)(1 << pSh);
    const float bin_w = fmaxf(rx2 - rx1, 1.0f) * invP;
    const float bin_h = fmaxf(ry2 - ry1, 1.0f) * invP;

    uint32_t off[8];          // byte offsets of paired loads within (b,chunk) slab
    float wlo[8], whi[8];
    #pragma unroll
    for (int qy = 0; qy < 2; ++qy) {
        float ys = ry1 + ((float)py + (qy ? 0.75f : 0.25f)) * bin_h;
        bool vy = (ys >= -1.0f) && (ys <= (float)HW);
        float y = fminf(fmaxf(ys, 0.0f), (float)(HW - 1));
        int y0 = (int)y;                               // y >= 0: trunc == floor
        int y1i = min(y0 + 1, HW - 1);
        float ly = y - (float)y0;
        float hy = 1.0f - ly;
        #pragma unroll
        for (int qx = 0; qx < 2; ++qx) {
            float xs = rx1 + ((float)px + (qx ? 0.75f : 0.25f)) * bin_w;
            bool vx = (xs >= -1.0f) && (xs <= (float)HW);
            float x = fminf(fmaxf(xs, 0.0f), (float)(HW - 1));
            int x0 = (int)x;
            float lx = x - (float)x0;
            float hx = 1.0f - lx;
            // pair base: clamp to HW-2 so the 8B load stays in-bounds; when
            // shifted, x0==HW-1 and lx==0, so value at slot hi carries hx.
            int xb = min(x0, HW - 2);
            float wx0 = (x0 == xb) ? hx : 0.0f;
            float wx1 = (x0 == xb) ? lx : hx;
            float vw = (vy && vx) ? 0.25f : 0.0f;      // 2x2-sample mean folded in
            int s = (qy * 2 + qx) * 2;
            off[s]     = (uint32_t)(((y0  << hwSh) + xb) * 4);
            wlo[s]     = vw * hy * wx0;  whi[s]     = vw * hy * wx1;
            off[s + 1] = (uint32_t)(((y1i << hwSh) + xb) * 4);
            wlo[s + 1] = vw * ly * wx0;  whi[s + 1] = vw * ly * wx1;
        }
    }

    // 32-bit byte offsets from SGPR bases (max feat slab 33.5 MB, out 418 MB).
    const uint32_t fbase = (uint32_t)((b * C_CH + chunk * CC) << (2 * hwSh)) * 4u;
    uint32_t o[8];
    #pragma unroll
    for (int i = 0; i < 8; ++i) o[i] = fbase + off[i];
    uint32_t soff = (uint32_t)(((m * C_CH + chunk * CC) << (2 * pSh)) + pib) * 4u;

    const uint32_t cStride = 4u << (2 * hwSh);        // HW2*4
    const uint32_t sStride = (uint32_t)K * 4u;

    #pragma unroll 2
    for (int c = 0; c < CC; ++c) {
        float acc = 0.0f;
        #pragma unroll
        for (int i = 0; i < 8; ++i) {
            F2 v = *(const F2*)(fB + o[i]);
            acc += wlo[i] * v.x + whi[i] * v.y;
            o[i] += cStride;
        }
        *(float*)(oB + soff) = acc;
        soff += sStride;
    }
}

extern "C" void kernel_launch(void* const* d_in, const int* in_sizes, int n_in,
                              void* d_out, int out_size, void* d_ws, size_t ws_size,
                              hipStream_t stream) {
    const int M = in_sizes[4] / 5;

    Params p;
    p.feat[0] = (const float*)d_in[0];  // [2,256,128,128]
    p.feat[1] = (const float*)d_in[1];  // [2,256,64,64]
    p.feat[2] = (const float*)d_in[2];  // [2,256,32,32]
    p.feat[3] = (const float*)d_in[3];  // [2,256,16,16]
    p.boxes   = (const float*)d_in[4];
    p.M = M;

    const float scales[4] = {0.125f, 0.0625f, 0.03125f, 0.015625f};
    const int hwSh[4] = {7, 6, 5, 4};   // 128,64,32,16
    const int pSh[4]  = {2, 3, 4, 5};   // 4,8,16,32

    long long ob = 0;
    int wb = 0;
    p.workBase[0] = 0;
    for (int l = 0; l < 4; ++l) {
        p.scale[l]   = scales[l];
        p.hwShift[l] = hwSh[l];
        p.pShift[l]  = pSh[l];
        p.outBase[l] = ob;
        int K = 1 << (2 * pSh[l]);
        ob += (long long)M * C_CH * K;
        int work = M * K * NCHUNK;
        wb += (work + 255) & ~255;      // pad so blocks never straddle levels
        p.workBase[l + 1] = wb;
    }

    int blocks = p.workBase[4] / 256;
    msroi_kernel<<<blocks, 256, 0, stream>>>(p, (float*)d_out);
}

// Round 4
// 252.708 us; speedup vs baseline: 1.5723x; 1.5723x over previous
//
#include <hip/hip_runtime.h>
#include <stdint.h>

// Fused multi-scale ROIAlign (torchvision, aligned=false, sampling_ratio=2).
// R4: strip-separable path for levels 2,3 (94% of outputs). The 2x2-sample
// mean + bilinear factorizes into separable X/Y kernels; a strip of S
// consecutive output pixels reads a fixed 3-row x WC-col feature window
// (bin sizes are bounded: L3 bin<=0.155px -> 8px strip in 4 cols; L2
// bin<=0.617 -> 4px strip in 5 cols). Per channel-iter: 3*WC offset-folded
// dword loads + S/4 float4 stores for S outputs, vs 16 gathers + 1 store
// PER output in the pixel path. Levels 0,1 (2.3% of outputs, wide bins)
// keep the proven R2 per-pixel path. One fused kernel, block-uniform level.

#define C_CH 256
#define CC 32                 // channels per thread
#define NCHUNK (C_CH / CC)

struct Params {
    const float* feat[4];
    const float* boxes;
    long long outBase[4];     // element offset into out (reference order L0..L3)
    float scale[4];
    int workBase[5];          // cumulative padded work items, kernel order L3,L2,L1,L0
    int M;
};

// ---------------- pixel path (levels 0,1) — R2 structure ----------------
template<int pSh, int hwSh>
__device__ __forceinline__ void pixel_body(
    const float* __restrict__ feat, const float* __restrict__ boxes,
    float* __restrict__ out, int r, int M, float sc)
{
    constexpr int HW = 1 << hwSh, HW2 = HW * HW, K = 1 << (2 * pSh);
    const int pixN = M << (2 * pSh);
    if (r >= pixN * NCHUNK) return;
    const int chunk = r / pixN;
    const int pix = r - chunk * pixN;
    const int m   = pix >> (2 * pSh);
    const int pib = pix & (K - 1);
    const int py  = pib >> pSh;
    const int px  = pib & ((1 << pSh) - 1);

    const float* bxp = boxes + m * 5;
    const int   b   = (int)bxp[0];
    const float rx1 = bxp[1] * sc, ry1 = bxp[2] * sc;
    const float rx2 = bxp[3] * sc, ry2 = bxp[4] * sc;
    const float invP  = 1.0f / (float)(1 << pSh);
    const float bin_w = fmaxf(rx2 - rx1, 1.0f) * invP;
    const float bin_h = fmaxf(ry2 - ry1, 1.0f) * invP;

    int off[16]; float w[16];
    #pragma unroll
    for (int qy = 0; qy < 2; ++qy) {
        float ys = ry1 + ((float)py + (qy ? 0.75f : 0.25f)) * bin_h;
        bool vy = (ys >= -1.0f) && (ys <= (float)HW);
        float y = fminf(fmaxf(ys, 0.0f), (float)(HW - 1));
        int y0 = (int)y, y1i = min(y0 + 1, HW - 1);
        float ly = y - (float)y0, hy = 1.0f - ly;
        #pragma unroll
        for (int qx = 0; qx < 2; ++qx) {
            float xs = rx1 + ((float)px + (qx ? 0.75f : 0.25f)) * bin_w;
            bool vx = (xs >= -1.0f) && (xs <= (float)HW);
            float x = fminf(fmaxf(xs, 0.0f), (float)(HW - 1));
            int x0 = (int)x, x1i = min(x0 + 1, HW - 1);
            float lx = x - (float)x0, hx = 1.0f - lx;
            float vw = (vy && vx) ? 0.25f : 0.0f;
            int s = (qy * 2 + qx) * 4;
            off[s + 0] = (y0  << hwSh) + x0;   w[s + 0] = vw * hy * hx;
            off[s + 1] = (y0  << hwSh) + x1i;  w[s + 1] = vw * hy * lx;
            off[s + 2] = (y1i << hwSh) + x0;   w[s + 2] = vw * ly * hx;
            off[s + 3] = (y1i << hwSh) + x1i;  w[s + 3] = vw * ly * lx;
        }
    }

    const float* fb = feat + (size_t)(b * C_CH + chunk * CC) * HW2;
    float* ob = out + (size_t)(m * C_CH + chunk * CC) * K + pib;
    #pragma unroll 2
    for (int c = 0; c < CC; ++c) {
        const float* fc = fb + c * HW2;
        float acc = 0.0f;
        #pragma unroll
        for (int i = 0; i < 16; ++i) acc += w[i] * fc[off[i]];
        ob[(size_t)c * K] = acc;
    }
}

// ---------------- strip-separable path (levels 2,3) ----------------
// S consecutive x-pixels (same py) share a 3-row x WC-col feature window.
template<int pSh, int hwSh, int S, int WC>
__device__ __forceinline__ void strip_body(
    const float* __restrict__ feat, const float* __restrict__ boxes,
    float* __restrict__ out, int r, int M, float sc)
{
    constexpr int HW = 1 << hwSh, HW2 = HW * HW, P = 1 << pSh, K = P * P;
    constexpr int NS = K / S;                 // strips per (m)
    static_assert(P / S == 4, "4 strips per row assumed");
    constexpr int lgNS = (NS == 128) ? 7 : (NS == 64 ? 6 : (NS == 32 ? 5 : 0));
    static_assert((1 << lgNS) == NS, "NS pow2");

    const int pixN = M * NS;
    if (r >= pixN * NCHUNK) return;
    const int chunk = r / pixN;
    const int t2    = r - chunk * pixN;
    const int m     = t2 >> lgNS;
    const int strip = t2 & (NS - 1);
    const int py    = strip >> 2;
    const int px0   = (strip & 3) * S;

    const float* bxp = boxes + m * 5;
    const int   b   = (int)bxp[0];
    const float rx1 = bxp[1] * sc, ry1 = bxp[2] * sc;
    const float rx2 = bxp[3] * sc, ry2 = bxp[4] * sc;
    const float invP  = 1.0f / (float)P;
    const float bin_w = fmaxf(rx2 - rx1, 1.0f) * invP;
    const float bin_h = fmaxf(ry2 - ry1, 1.0f) * invP;

    // Y weights (shared across the strip): 3-row window starting at rb.
    float WY[3] = {0.0f, 0.0f, 0.0f};
    int rb;
    {
        float ysf = ry1 + ((float)py + 0.25f) * bin_h;
        float yf  = fminf(fmaxf(ysf, 0.0f), (float)(HW - 1));
        rb = min((int)yf, HW - 3);
        #pragma unroll
        for (int qy = 0; qy < 2; ++qy) {
            float ys = ry1 + ((float)py + (qy ? 0.75f : 0.25f)) * bin_h;
            bool vy = (ys >= -1.0f) && (ys <= (float)HW);
            float y = fminf(fmaxf(ys, 0.0f), (float)(HW - 1));
            int y0 = (int)y, y1i = min(y0 + 1, HW - 1);
            float ly = y - (float)y0;
            float w0 = vy ? 0.5f * (1.0f - ly) : 0.0f;   // 0.5 = mean over 2 qy
            float w1 = vy ? 0.5f * ly          : 0.0f;
            int s0 = y0 - rb, s1 = y1i - rb;
            #pragma unroll
            for (int j = 0; j < 3; ++j)
                WY[j] += (s0 == j ? w0 : 0.0f) + (s1 == j ? w1 : 0.0f);
        }
    }

    // X weights per strip pixel: WC-col window starting at cb.
    float WX[S][WC];
    int cb;
    {
        float xsf = rx1 + ((float)px0 + 0.25f) * bin_w;
        float xf  = fminf(fmaxf(xsf, 0.0f), (float)(HW - 1));
        cb = min((int)xf, HW - WC);
        #pragma unroll
        for (int s = 0; s < S; ++s) {
            #pragma unroll
            for (int i = 0; i < WC; ++i) WX[s][i] = 0.0f;
            #pragma unroll
            for (int qx = 0; qx < 2; ++qx) {
                float xs = rx1 + ((float)(px0 + s) + (qx ? 0.75f : 0.25f)) * bin_w;
                bool vx = (xs >= -1.0f) && (xs <= (float)HW);
                float x = fminf(fmaxf(xs, 0.0f), (float)(HW - 1));
                int x0 = (int)x, x1i = min(x0 + 1, HW - 1);
                float lx = x - (float)x0;
                float w0 = vx ? 0.5f * (1.0f - lx) : 0.0f; // 0.5 = mean over 2 qx
                float w1 = vx ? 0.5f * lx          : 0.0f;
                int s0 = x0 - cb, s1 = x1i - cb;
                #pragma unroll
                for (int i = 0; i < WC; ++i)
                    WX[s][i] += (s0 == i ? w0 : 0.0f) + (s1 == i ? w1 : 0.0f);
            }
        }
    }

    const float* pf = feat + (size_t)((b * C_CH + chunk * CC) * HW2 + rb * HW + cb);
    float* po = out + (size_t)(((m * C_CH + chunk * CC) << (2 * pSh)) + (py << pSh) + px0);

    #pragma unroll 2
    for (int c = 0; c < CC; ++c) {
        float f[3][WC];
        #pragma unroll
        for (int j = 0; j < 3; ++j)
            #pragma unroll
            for (int i = 0; i < WC; ++i)
                f[j][i] = pf[j * HW + i];          // offset-folded dword loads

        float acc[S];
        #pragma unroll
        for (int s = 0; s < S; ++s) acc[s] = 0.0f;
        #pragma unroll
        for (int j = 0; j < 3; ++j) {
            #pragma unroll
            for (int s = 0; s < S; ++s) {
                float rs = 0.0f;
                #pragma unroll
                for (int i = 0; i < WC; ++i) rs += WX[s][i] * f[j][i];
                acc[s] += WY[j] * rs;
            }
        }
        #pragma unroll
        for (int s = 0; s < S; s += 4)             // px0 multiple of 4 -> 16B aligned
            *(float4*)(po + s) = make_float4(acc[s], acc[s+1], acc[s+2], acc[s+3]);
        pf += HW2;
        po += K;
    }
}

__global__ __launch_bounds__(256, 4) void msroi_kernel(Params p, float* __restrict__ out)
{
    const int blockStart = blockIdx.x * 256;      // blocks never straddle levels
    const int lvl = (blockStart >= p.workBase[1])
                  + (blockStart >= p.workBase[2])
                  + (blockStart >= p.workBase[3]);
    const int r = blockStart + (int)threadIdx.x - p.workBase[lvl];
    // kernel work order: 0->L3 strips, 1->L2 strips, 2->L1 pixels, 3->L0 pixels
    if (lvl == 0)
        strip_body<5, 4, 8, 4>(p.feat[3], p.boxes, out + p.outBase[3], r, p.M, p.scale[3]);
    else if (lvl == 1)
        strip_body<4, 5, 4, 5>(p.feat[2], p.boxes, out + p.outBase[2], r, p.M, p.scale[2]);
    else if (lvl == 2)
        pixel_body<3, 6>(p.feat[1], p.boxes, out + p.outBase[1], r, p.M, p.scale[1]);
    else
        pixel_body<2, 7>(p.feat[0], p.boxes, out + p.outBase[0], r, p.M, p.scale[0]);
}

extern "C" void kernel_launch(void* const* d_in, const int* in_sizes, int n_in,
                              void* d_out, int out_size, void* d_ws, size_t ws_size,
                              hipStream_t stream) {
    const int M = in_sizes[4] / 5;

    Params p;
    p.feat[0] = (const float*)d_in[0];  // [2,256,128,128]
    p.feat[1] = (const float*)d_in[1];  // [2,256,64,64]
    p.feat[2] = (const float*)d_in[2];  // [2,256,32,32]
    p.feat[3] = (const float*)d_in[3];  // [2,256,16,16]
    p.boxes   = (const float*)d_in[4];
    p.M = M;
    const float scales[4] = {0.125f, 0.0625f, 0.03125f, 0.015625f};
    for (int l = 0; l < 4; ++l) p.scale[l] = scales[l];

    // Output bases in reference return order (L0..L3).
    p.outBase[0] = 0;
    p.outBase[1] = p.outBase[0] + (long long)M * C_CH * 4 * 4;
    p.outBase[2] = p.outBase[1] + (long long)M * C_CH * 8 * 8;
    p.outBase[3] = p.outBase[2] + (long long)M * C_CH * 16 * 16;

    // Work sizes, kernel order L3,L2 (strips of 8/4), L1,L0 (pixels), padded to 256.
    const int work[4] = {
        M * NCHUNK * (32 * 32 / 8),   // L3 strips
        M * NCHUNK * (16 * 16 / 4),   // L2 strips
        M * NCHUNK * (8 * 8),         // L1 pixels
        M * NCHUNK * (4 * 4)          // L0 pixels
    };
    p.workBase[0] = 0;
    for (int i = 0; i < 4; ++i)
        p.workBase[i + 1] = p.workBase[i] + ((work[i] + 255) & ~255);

    const int blocks = p.workBase[4] / 256;
    msroi_kernel<<<blocks, 256, 0, stream>>>(p, (float*)d_out);
}